// Round 1
// baseline (3070.995 us; speedup 1.0000x reference)
//
#include <hip/hip_runtime.h>

typedef unsigned short u16;
typedef unsigned int   u32;
typedef short  s16x8 __attribute__((ext_vector_type(8)));
typedef int    i32x4 __attribute__((ext_vector_type(4)));
typedef float  f32x4 __attribute__((ext_vector_type(4)));

// ---------- helpers ----------
__device__ __forceinline__ u16 f2bf(float f) {
    u32 u = __builtin_bit_cast(u32, f);
    u += 0x7FFFu + ((u >> 16) & 1u);   // RNE
    return (u16)(u >> 16);
}

__device__ __forceinline__ u32 pkbf2(float a, float b) {
    return (u32)f2bf(a) | ((u32)f2bf(b) << 16);
}

__device__ __forceinline__ void gl2lds16(const void* g, void* l) {
    __builtin_amdgcn_global_load_lds((const __attribute__((address_space(1))) void*)g,
                                     (__attribute__((address_space(3))) void*)l, 16, 0, 0);
}

#define MFMA16(a, b, c) __builtin_amdgcn_mfma_f32_16x16x32_bf16((a), (b), (c), 0, 0, 0)

// ---------- weight repack: int32 [O,I] (one int4/elem) -> u32 [O, I/8] ----------
__global__ __launch_bounds__(256)
void pack_w4(const int* __restrict__ W, u32* __restrict__ P, int n8)
{
    for (int i = blockIdx.x * 256 + threadIdx.x; i < n8; i += gridDim.x * 256) {
        const int4* p = (const int4*)(W + (size_t)i * 8);
        const int4 a = p[0], b = p[1];
        const u32 r = ((u32)a.x & 15u)         | (((u32)a.y & 15u) << 4)
                    | (((u32)a.z & 15u) << 8)  | (((u32)a.w & 15u) << 12)
                    | (((u32)b.x & 15u) << 16) | (((u32)b.y & 15u) << 20)
                    | (((u32)b.z & 15u) << 24) | (((u32)b.w & 15u) << 28);
        P[i] = r;
    }
}

// ---------- RMSNorm: f32 [T,4096] -> bf16 [T,4096] ----------
__global__ __launch_bounds__(256)
void rmsnorm_k(const float* __restrict__ x, const float* __restrict__ g, u16* __restrict__ o)
{
    const int t = blockIdx.x;
    const int tid = threadIdx.x;
    const float4* row = (const float4*)(x + (size_t)t * 4096);
    float4 v[4];
    float ss = 0.f;
#pragma unroll
    for (int i = 0; i < 4; ++i) {
        v[i] = row[tid + i * 256];
        ss += v[i].x * v[i].x + v[i].y * v[i].y + v[i].z * v[i].z + v[i].w * v[i].w;
    }
#pragma unroll
    for (int off = 32; off >= 1; off >>= 1) ss += __shfl_xor(ss, off);
    __shared__ float red[4];
    if ((tid & 63) == 0) red[tid >> 6] = ss;
    __syncthreads();
    const float tot = red[0] + red[1] + red[2] + red[3];
    const float rs = rsqrtf(tot * (1.0f / 4096.0f) + 1e-5f);
    const float4* gw = (const float4*)g;
    uint2* orow = (uint2*)(o + (size_t)t * 4096);
#pragma unroll
    for (int i = 0; i < 4; ++i) {
        float4 wv = gw[tid + i * 256];
        uint2 pk;
        pk.x = pkbf2(v[i].x * rs * wv.x, v[i].y * rs * wv.y);
        pk.y = pkbf2(v[i].z * rs * wv.z, v[i].w * rs * wv.w);
        orow[tid + i * 256] = pk;
    }
}

// ---------- W4A16 GEMM core (packed weights) ----------
// BM=BN=128, BK=64, 256 threads. Wave w owns output cols [w*32, w*32+32).
// A: LDS double-buffer (2 x 16 KB), async DMA. W: nibble-packed u32 (8 wt/u32),
// dequantized directly into MFMA B-fragments in registers. One barrier per K-step.
// epi 0: bf16 row-major; epi 1: bf16 V-transposed; epi 2: f32 +resid; epi 3: bf16 relu^2
template<int KDIM>
__device__ __forceinline__ void gemm_core(
    const u16* __restrict__ A, const u32* __restrict__ W,
    const float* __restrict__ Sc, const float* __restrict__ Zp,
    void* __restrict__ outp, const float* __restrict__ resid,
    int ldc, int epi, int m0, int n0)
{
    constexpr int NG = KDIM / 128;
    constexpr int KT = KDIM / 64;          // K-steps
    constexpr int KP = KDIM / 8;           // packed u32 per weight row
    const int tid = threadIdx.x;
    const int w = tid >> 6, l = tid & 63;
    const int quad = l >> 4, lr = l & 15;

    extern __shared__ char smem[];
    u16* const As0 = (u16*)smem;           // 128 x 64, chunk-xor swizzle
    u16* const As1 = (u16*)(smem + 16384);

    // A DMA mapping: issue i covers rows seg..seg+7; lane l -> row seg+(l>>3), phys chunk l&7
    const int ar = l >> 3;
    const int ac = (l & 7) ^ ar;           // fetch global chunk so phys = global ^ (row&7)

    // W per-lane fragment rows: j=0,1 -> n0 + w*32 + j*16 + lr; k offset quad*8
    const int nr0 = n0 + w * 32 + lr;
    const int nr1 = nr0 + 16;
    const u32* Wp0 = W + (size_t)nr0 * KP + quad;
    const u32* Wp1 = W + (size_t)nr1 * KP + quad;
    const float* Sb0 = Sc + (size_t)nr0 * NG;
    const float* Zb0 = Zp + (size_t)nr0 * NG;
    const float* Sb1 = Sc + (size_t)nr1 * NG;
    const float* Zb1 = Zp + (size_t)nr1 * NG;

    f32x4 acc[8][2] = {};

    // wr[0..1]: row nr0 kh=0/1; wr[2..3]: row nr1 kh=0/1. u32 idx = kk*8 + kh*4 + quad.
    auto loadW = [&](u32 wr[4], float* sv, float* zv, int ki) {
        const int kk = (ki < KT) ? ki : 0;
        const int k8 = kk << 3, g = kk >> 1;
        wr[0] = Wp0[k8]; wr[1] = Wp0[k8 + 4];
        wr[2] = Wp1[k8]; wr[3] = Wp1[k8 + 4];
        sv[0] = Sb0[g]; zv[0] = Zb0[g];
        sv[1] = Sb1[g]; zv[1] = Zb1[g];
    };
    auto dmaA = [&](u16* dst, int ki) {
        const int k0 = ((ki < KT) ? ki : 0) << 6;
#pragma unroll
        for (int i = 0; i < 4; ++i) {
            const int seg = (w * 4 + i) * 8;
            gl2lds16(A + (size_t)(m0 + seg + ar) * KDIM + k0 + ac * 8, &dst[seg * 64]);
        }
    };
    auto dqfrag = [&](s16x8 fr[2][2], const u32 wr[4], const float* sv, const float* zv) {
#pragma unroll
        for (int j = 0; j < 2; ++j) {
            const float s = sv[j], nzs = -zv[j] * sv[j];
#pragma unroll
            for (int kh = 0; kh < 2; ++kh) {
                const u32 ww = wr[j * 2 + kh];
                i32x4 t;
#pragma unroll
                for (int q = 0; q < 4; ++q) {
                    const float lo = (float)((ww >> (8 * q)) & 15u);
                    const float hi = (float)((ww >> (8 * q + 4)) & 15u);
                    t[q] = (int)pkbf2(fmaf(lo, s, nzs), fmaf(hi, s, nzs));
                }
                fr[j][kh] = __builtin_bit_cast(s16x8, t);
            }
        }
    };
    auto comp = [&](const u16* Asr, s16x8 fr[2][2]) {
#pragma unroll
        for (int kh = 0; kh < 2; ++kh) {
            const int cc = kh * 4 + quad;
            s16x8 af[8];
#pragma unroll
            for (int i = 0; i < 8; ++i) {
                const int r = i * 16 + lr;
                af[i] = *(const s16x8*)&Asr[r * 64 + ((cc ^ (r & 7)) << 3)];
            }
#pragma unroll
            for (int i = 0; i < 8; ++i) {
                acc[i][0] = MFMA16(af[i], fr[0][kh], acc[i][0]);
                acc[i][1] = MFMA16(af[i], fr[1][kh], acc[i][1]);
            }
        }
    };

    // prologue
    u32 wrX[4], wrY[4];
    float svX[2], zvX[2], svY[2], zvY[2];
    s16x8 frX[2][2], frY[2][2];
    loadW(wrX, svX, zvX, 0);
    loadW(wrY, svY, zvY, 1);
    dmaA(As0, 0);
    dqfrag(frX, wrX, svX, zvX);        // frags for k=0
    loadW(wrX, svX, zvX, 2);
    __syncthreads();

    for (int kt = 0; kt < KT; kt += 2) {
        // stage: A(kt+1)->As1, frags(kt+1) from wrY; compute k=kt on As0/frX
        dmaA(As1, kt + 1);
        dqfrag(frY, wrY, svY, zvY);
        loadW(wrY, svY, zvY, kt + 3);
        comp(As0, frX);
        __syncthreads();
        // stage: A(kt+2)->As0, frags(kt+2) from wrX; compute k=kt+1 on As1/frY
        dmaA(As0, kt + 2);
        dqfrag(frX, wrX, svX, zvX);
        loadW(wrX, svX, zvX, kt + 4);
        comp(As1, frY);
        __syncthreads();
    }

    // epilogue: C row = m0 + i*16 + quad*4 + r ; col = n0 + w*32 + j*16 + lr
#pragma unroll
    for (int i = 0; i < 8; ++i) {
        const int rr0 = m0 + i * 16 + (quad << 2);
#pragma unroll
        for (int j = 0; j < 2; ++j) {
            const int cc = n0 + w * 32 + j * 16 + lr;
#pragma unroll
            for (int r = 0; r < 4; ++r) {
                const int row = rr0 + r;
                const float v = acc[i][j][r];
                if (epi == 0) {
                    ((u16*)outp)[(size_t)row * ldc + cc] = f2bf(v);
                } else if (epi == 1) {
                    ((u16*)outp)[((size_t)((row >> 10 << 10) + cc)) * 1024 + (row & 1023)] = f2bf(v);
                } else if (epi == 2) {
                    ((float*)outp)[(size_t)row * ldc + cc] = v + resid[(size_t)row * ldc + cc];
                } else {
                    const float t = v > 0.f ? v : 0.f;
                    ((u16*)outp)[(size_t)row * ldc + cc] = f2bf(t * t);
                }
            }
        }
    }
}

template<int KDIM>
__global__ __launch_bounds__(256, 3)
void gemm_w4(const u16* __restrict__ A, const u32* __restrict__ W,
             const float* __restrict__ Sc, const float* __restrict__ Zp,
             void* __restrict__ outp, const float* __restrict__ resid, int ldc, int epi)
{
    gemm_core<KDIM>(A, W, Sc, Zp, outp, resid, ldc, epi, blockIdx.x << 7, blockIdx.y << 7);
}

// fused QKV: ny 0..31 -> Q, 32..39 -> K, 40..47 -> V(transposed)
__global__ __launch_bounds__(256, 3)
void qkv_w4(const u16* __restrict__ A,
            const u32* __restrict__ qW, const float* __restrict__ qS, const float* __restrict__ qZ,
            const u32* __restrict__ kW, const float* __restrict__ kS, const float* __restrict__ kZ,
            const u32* __restrict__ vW, const float* __restrict__ vS, const float* __restrict__ vZ,
            u16* __restrict__ qout, u16* __restrict__ kout, u16* __restrict__ vtout)
{
    const int ny = blockIdx.y;
    const int m0 = blockIdx.x << 7;
    if (ny < 32)
        gemm_core<4096>(A, qW, qS, qZ, (void*)qout, nullptr, 4096, 0, m0, ny << 7);
    else if (ny < 40)
        gemm_core<4096>(A, kW, kS, kZ, (void*)kout, nullptr, 1024, 0, m0, (ny - 32) << 7);
    else
        gemm_core<4096>(A, vW, vS, vZ, (void*)vtout, nullptr, 1024, 1, m0, (ny - 40) << 7);
}

// ---------- Flash attention (causal, GQA 32q/8kv, HD=128, S=1024) ----------
__global__ __launch_bounds__(256)
void attn_k(const u16* __restrict__ Q, const u16* __restrict__ K,
            const u16* __restrict__ Vt, u16* __restrict__ O)
{
    const int qt = blockIdx.x, h = blockIdx.y, b = blockIdx.z;
    const int kh = h >> 2;
    const int tid = threadIdx.x, w = tid >> 6, l = tid & 63;
    const int quad = l >> 4, lr = l & 15;
    const int q0 = qt << 6;

    __shared__ __align__(16) u16 Qs[64 * 128];
    __shared__ __align__(16) u16 Ks[64 * 128];
    __shared__ __align__(16) u16 Vs[128 * 64];
    __shared__ __align__(16) u16 Ps[64 * 72];

#pragma unroll
    for (int i = 0; i < 4; ++i) {
        const int L = i * 256 + w * 64 + l;
        const int row = L >> 4, cl = L & 15;
        const int c = cl ^ (row & 15);
        gl2lds16(Q + ((size_t)(b * 1024 + q0 + row) * 4096 + h * 128 + c * 8),
                 &Qs[(i * 256 + w * 64) * 8]);
    }
    __syncthreads();
    s16x8 qf[4];
#pragma unroll
    for (int ks = 0; ks < 4; ++ks) {
        const int rq = w * 16 + lr;
        const int c = ks * 4 + quad;
        qf[ks] = *(const s16x8*)&Qs[rq * 128 + ((c ^ (rq & 15)) << 3)];
    }

    float m_i[4] = {-__builtin_inff(), -__builtin_inff(), -__builtin_inff(), -__builtin_inff()};
    float l_i[4] = {0.f, 0.f, 0.f, 0.f};
    f32x4 oa[8] = {};

    for (int n0 = 0; n0 <= q0; n0 += 64) {
        __syncthreads();
#pragma unroll
        for (int i = 0; i < 4; ++i) {
            const int L = i * 256 + w * 64 + l;
            const int row = L >> 4, cl = L & 15;
            const int c = cl ^ (row & 15);
            gl2lds16(K + ((size_t)(b * 1024 + n0 + row) * 1024 + kh * 128 + c * 8),
                     &Ks[(i * 256 + w * 64) * 8]);
        }
#pragma unroll
        for (int i = 0; i < 4; ++i) {
            const int L = i * 256 + w * 64 + l;
            const int d = L >> 3, cl = L & 7;
            const int c = cl ^ (d & 7);
            gl2lds16(Vt + ((size_t)((b * 8 + kh) * 128 + d) * 1024 + n0 + c * 8),
                     &Vs[(i * 256 + w * 64) * 8]);
        }
        __syncthreads();

        f32x4 sc[4] = {};
#pragma unroll
        for (int ks = 0; ks < 4; ++ks) {
#pragma unroll
            for (int ni = 0; ni < 4; ++ni) {
                const int n = ni * 16 + lr;
                const int c = ks * 4 + quad;
                s16x8 bk = *(const s16x8*)&Ks[n * 128 + ((c ^ (n & 15)) << 3)];
                sc[ni] = MFMA16(qf[ks], bk, sc[ni]);
            }
        }
        const float scale = 0.08838834764831845f;
        const bool diag = (n0 == q0);
#pragma unroll
        for (int ni = 0; ni < 4; ++ni) {
            const int nabs = n0 + ni * 16 + lr;
#pragma unroll
            for (int r = 0; r < 4; ++r) {
                float vv = sc[ni][r] * scale;
                if (diag && nabs > q0 + w * 16 + quad * 4 + r) vv = -__builtin_inff();
                sc[ni][r] = vv;
            }
        }
        float alpha[4];
#pragma unroll
        for (int r = 0; r < 4; ++r) {
            float mx = fmaxf(fmaxf(sc[0][r], sc[1][r]), fmaxf(sc[2][r], sc[3][r]));
            mx = fmaxf(mx, __shfl_xor(mx, 1));
            mx = fmaxf(mx, __shfl_xor(mx, 2));
            mx = fmaxf(mx, __shfl_xor(mx, 4));
            mx = fmaxf(mx, __shfl_xor(mx, 8));
            const float mn = fmaxf(m_i[r], mx);
            alpha[r] = __expf(m_i[r] - mn);
            m_i[r] = mn;
#pragma unroll
            for (int ni = 0; ni < 4; ++ni) sc[ni][r] = __expf(sc[ni][r] - mn);
            float sr = sc[0][r] + sc[1][r] + sc[2][r] + sc[3][r];
            sr += __shfl_xor(sr, 1); sr += __shfl_xor(sr, 2);
            sr += __shfl_xor(sr, 4); sr += __shfl_xor(sr, 8);
            l_i[r] = l_i[r] * alpha[r] + sr;
        }
#pragma unroll
        for (int dt = 0; dt < 8; ++dt)
#pragma unroll
            for (int r = 0; r < 4; ++r) oa[dt][r] *= alpha[r];
#pragma unroll
        for (int ni = 0; ni < 4; ++ni)
#pragma unroll
            for (int r = 0; r < 4; ++r)
                Ps[(w * 16 + quad * 4 + r) * 72 + ni * 16 + lr] = f2bf(sc[ni][r]);
        __syncthreads();
#pragma unroll
        for (int ks = 0; ks < 2; ++ks) {
            s16x8 pa = *(const s16x8*)&Ps[(w * 16 + lr) * 72 + ks * 32 + (quad << 3)];
#pragma unroll
            for (int dt = 0; dt < 8; ++dt) {
                const int d = dt * 16 + lr;
                const int c = ks * 4 + quad;
                s16x8 bv = *(const s16x8*)&Vs[(d << 6) + ((c ^ (d & 7)) << 3)];
                oa[dt] = MFMA16(pa, bv, oa[dt]);
            }
        }
    }
#pragma unroll
    for (int dt = 0; dt < 8; ++dt) {
#pragma unroll
        for (int r = 0; r < 4; ++r) {
            const int row = q0 + w * 16 + quad * 4 + r;
            const int col = h * 128 + dt * 16 + lr;
            O[(size_t)(b * 1024 + row) * 4096 + col] = f2bf(oa[dt][r] / l_i[r]);
        }
    }
}

// ---------- launch ----------
extern "C" void kernel_launch(void* const* d_in, const int* in_sizes, int n_in,
                              void* d_out, int out_size, void* d_ws, size_t ws_size,
                              hipStream_t stream)
{
    (void)in_sizes; (void)n_in; (void)out_size; (void)ws_size;
    const float* hidden = (const float*)d_in[0];
    const float* ln1 = (const float*)d_in[1];
    const float* ln2 = (const float*)d_in[2];
    const int*   q_qw = (const int*)d_in[3];
    const float* q_s  = (const float*)d_in[4];
    const float* q_z  = (const float*)d_in[5];
    const int*   k_qw = (const int*)d_in[6];
    const float* k_s  = (const float*)d_in[7];
    const float* k_z  = (const float*)d_in[8];
    const int*   v_qw = (const int*)d_in[9];
    const float* v_s  = (const float*)d_in[10];
    const float* v_z  = (const float*)d_in[11];
    const int*   o_qw = (const int*)d_in[12];
    const float* o_s  = (const float*)d_in[13];
    const float* o_z  = (const float*)d_in[14];
    const int*   up_qw = (const int*)d_in[15];
    const float* up_s  = (const float*)d_in[16];
    const float* up_z  = (const float*)d_in[17];
    const int*   dn_qw = (const int*)d_in[18];
    const float* dn_s  = (const float*)d_in[19];
    const float* dn_z  = (const float*)d_in[20];
    float* out = (float*)d_out;
    char* ws = (char*)d_ws;

    // ---- workspace layout (peak ~138.5 MB) ----
    float* x_buf  = (float*)(ws);                 // f32 [2048][4096]   0..32M
    u16* h_buf    = (u16*)(ws + 33554432);        // bf16 [2048][4096]  32..48M (h and h2)
    u32* P        = (u32*)(ws + 50331648);        // packed-weight pool 48..77.4M (<=29.36MB)
    u16* q_buf    = (u16*)(ws + 79691776);        // attn-phase buffers 76..116M
    u16* k_buf    = (u16*)(ws + 96468992);
    u16* vt_buf   = (u16*)(ws + 100663296);
    u16* attn_buf = (u16*)(ws + 104857600);
    u16* act_buf  = (u16*)(ws + 79691776);        // overlays q/k/vt/attn in MLP phase
    u16* h2_buf   = h_buf;

    // packed sub-buffers (pool reused sequentially: {q,k,v} -> o -> up -> dn)
    u32* Pq  = P;                  // 4096*512  u32
    u32* Pk  = P + 2097152;        // 1024*512
    u32* Pv  = P + 2621440;        // 1024*512
    u32* Po  = P;                  // 4096*512
    u32* Pup = P;                  // 14336*512
    u32* Pdn = P;                  // 4096*1792

    // attention phase
    pack_w4<<<2048, 256, 0, stream>>>(q_qw, Pq, 4096 * 512);
    pack_w4<<<1024, 256, 0, stream>>>(k_qw, Pk, 1024 * 512);
    pack_w4<<<1024, 256, 0, stream>>>(v_qw, Pv, 1024 * 512);
    rmsnorm_k<<<2048, 256, 0, stream>>>(hidden, ln1, h_buf);
    qkv_w4<<<dim3(16, 48), 256, 32768, stream>>>(h_buf,
        Pq, q_s, q_z, Pk, k_s, k_z, Pv, v_s, v_z,
        q_buf, k_buf, vt_buf);
    attn_k<<<dim3(16, 32, 2), 256, 0, stream>>>(q_buf, k_buf, vt_buf, attn_buf);
    pack_w4<<<2048, 256, 0, stream>>>(o_qw, Po, 4096 * 512);
    gemm_w4<4096><<<dim3(16, 32), 256, 32768, stream>>>(attn_buf, Po, o_s, o_z,
        (void*)x_buf, hidden, 4096, 2);

    // MLP phase
    rmsnorm_k<<<2048, 256, 0, stream>>>(x_buf, ln2, h2_buf);
    pack_w4<<<2048, 256, 0, stream>>>(up_qw, Pup, 14336 * 512);
    gemm_w4<4096><<<dim3(16, 112), 256, 32768, stream>>>(h2_buf, Pup, up_s, up_z,
        (void*)act_buf, nullptr, 14336, 3);
    pack_w4<<<2048, 256, 0, stream>>>(dn_qw, Pdn, 4096 * 1792);
    gemm_w4<14336><<<dim3(16, 32), 256, 32768, stream>>>(act_buf, Pdn, dn_s, dn_z,
        (void*)out, x_buf, 4096, 2);
}

// Round 3
// 2223.078 us; speedup vs baseline: 1.3814x; 1.3814x over previous
//
#include <hip/hip_runtime.h>

typedef unsigned short u16;
typedef unsigned int   u32;
typedef short  s16x8 __attribute__((ext_vector_type(8)));
typedef int    i32x4 __attribute__((ext_vector_type(4)));
typedef float  f32x4 __attribute__((ext_vector_type(4)));

// ---------- helpers ----------
__device__ __forceinline__ u16 f2bf(float f) {
    u32 u = __builtin_bit_cast(u32, f);
    u += 0x7FFFu + ((u >> 16) & 1u);   // RNE
    return (u16)(u >> 16);
}

__device__ __forceinline__ u32 pkbf2(float a, float b) {
    return (u32)f2bf(a) | ((u32)f2bf(b) << 16);
}

__device__ __forceinline__ void gl2lds16(const void* g, void* l) {
    __builtin_amdgcn_global_load_lds((const __attribute__((address_space(1))) void*)g,
                                     (__attribute__((address_space(3))) void*)l, 16, 0, 0);
}

#define MFMA16(a, b, c) __builtin_amdgcn_mfma_f32_16x16x32_bf16((a), (b), (c), 0, 0, 0)

// ---------- weight repack: int32 [O,I] (one int4/elem) -> u32 [O, I/8] (linear) ----------
__global__ __launch_bounds__(256)
void pack_w4(const int* __restrict__ W, u32* __restrict__ P, int n8)
{
    for (int i = blockIdx.x * 256 + threadIdx.x; i < n8; i += gridDim.x * 256) {
        const int4* p = (const int4*)(W + (size_t)i * 8);
        const int4 a = p[0], b = p[1];
        const u32 r = ((u32)a.x & 15u)         | (((u32)a.y & 15u) << 4)
                    | (((u32)a.z & 15u) << 8)  | (((u32)a.w & 15u) << 12)
                    | (((u32)b.x & 15u) << 16) | (((u32)b.y & 15u) << 20)
                    | (((u32)b.z & 15u) << 24) | (((u32)b.w & 15u) << 28);
        P[i] = r;
    }
}

// ---------- RMSNorm: f32 [T,4096] -> bf16 [T,4096] ----------
__global__ __launch_bounds__(256)
void rmsnorm_k(const float* __restrict__ x, const float* __restrict__ g, u16* __restrict__ o)
{
    const int t = blockIdx.x;
    const int tid = threadIdx.x;
    const float4* row = (const float4*)(x + (size_t)t * 4096);
    float4 v[4];
    float ss = 0.f;
#pragma unroll
    for (int i = 0; i < 4; ++i) {
        v[i] = row[tid + i * 256];
        ss += v[i].x * v[i].x + v[i].y * v[i].y + v[i].z * v[i].z + v[i].w * v[i].w;
    }
#pragma unroll
    for (int off = 32; off >= 1; off >>= 1) ss += __shfl_xor(ss, off);
    __shared__ float red[4];
    if ((tid & 63) == 0) red[tid >> 6] = ss;
    __syncthreads();
    const float tot = red[0] + red[1] + red[2] + red[3];
    const float rs = rsqrtf(tot * (1.0f / 4096.0f) + 1e-5f);
    const float4* gw = (const float4*)g;
    uint2* orow = (uint2*)(o + (size_t)t * 4096);
#pragma unroll
    for (int i = 0; i < 4; ++i) {
        float4 wv = gw[tid + i * 256];
        uint2 pk;
        pk.x = pkbf2(v[i].x * rs * wv.x, v[i].y * rs * wv.y);
        pk.y = pkbf2(v[i].z * rs * wv.z, v[i].w * rs * wv.w);
        orow[tid + i * 256] = pk;
    }
}

// ---------- W4A16 GEMM core (packed weights, linear layout) ----------
// BM=BN=128, BK=64, 256 threads. Wave w owns output cols [w*32, w*32+32).
// A: LDS double-buffer (2 x 16 KB), async DMA. W: nibble-packed u32 (8 wt/u32),
// dequantized directly into MFMA B-fragments in registers. One barrier per K-step.
// epi 0: bf16 row-major; epi 1: bf16 V-transposed; epi 2: f32 +resid; epi 3: bf16 relu^2
template<int KDIM>
__device__ __forceinline__ void gemm_core(
    const u16* __restrict__ A, const u32* __restrict__ W,
    const float* __restrict__ Sc, const float* __restrict__ Zp,
    void* __restrict__ outp, const float* __restrict__ resid,
    int ldc, int epi, int m0, int n0)
{
    constexpr int NG = KDIM / 128;
    constexpr int KT = KDIM / 64;          // K-steps
    constexpr int KP = KDIM / 8;           // packed u32 per weight row
    const int tid = threadIdx.x;
    const int w = tid >> 6, l = tid & 63;
    const int quad = l >> 4, lr = l & 15;

    extern __shared__ char smem[];
    u16* const As0 = (u16*)smem;           // 128 x 64, chunk-xor swizzle
    u16* const As1 = (u16*)(smem + 16384);

    // A DMA mapping: issue i covers rows seg..seg+7; lane l -> row seg+(l>>3), phys chunk l&7
    const int ar = l >> 3;
    const int ac = (l & 7) ^ ar;           // fetch global chunk so phys = global ^ (row&7)

    // W per-lane fragment rows: j=0,1 -> n0 + w*32 + j*16 + lr; k offset quad*8
    const int nr0 = n0 + w * 32 + lr;
    const int nr1 = nr0 + 16;
    const u32* Wp0 = W + (size_t)nr0 * KP + quad;
    const u32* Wp1 = W + (size_t)nr1 * KP + quad;
    const float* Sb0 = Sc + (size_t)nr0 * NG;
    const float* Zb0 = Zp + (size_t)nr0 * NG;
    const float* Sb1 = Sc + (size_t)nr1 * NG;
    const float* Zb1 = Zp + (size_t)nr1 * NG;

    f32x4 acc[8][2] = {};

    // wr[0..1]: row nr0 kh=0/1; wr[2..3]: row nr1 kh=0/1. u32 idx = kk*8 + kh*4 + quad.
    auto loadW = [&](u32 wr[4], float* sv, float* zv, int ki) {
        const int kk = (ki < KT) ? ki : 0;
        const int k8 = kk << 3, g = kk >> 1;
        wr[0] = Wp0[k8]; wr[1] = Wp0[k8 + 4];
        wr[2] = Wp1[k8]; wr[3] = Wp1[k8 + 4];
        sv[0] = Sb0[g]; zv[0] = Zb0[g];
        sv[1] = Sb1[g]; zv[1] = Zb1[g];
    };
    auto dmaA = [&](u16* dst, int ki) {
        const int k0 = ((ki < KT) ? ki : 0) << 6;
#pragma unroll
        for (int i = 0; i < 4; ++i) {
            const int seg = (w * 4 + i) * 8;
            gl2lds16(A + (size_t)(m0 + seg + ar) * KDIM + k0 + ac * 8, &dst[seg * 64]);
        }
    };
    auto dqfrag = [&](s16x8 fr[2][2], const u32 wr[4], const float* sv, const float* zv) {
#pragma unroll
        for (int j = 0; j < 2; ++j) {
            const float s = sv[j], nzs = -zv[j] * sv[j];
#pragma unroll
            for (int kh = 0; kh < 2; ++kh) {
                const u32 ww = wr[j * 2 + kh];
                i32x4 t;
#pragma unroll
                for (int q = 0; q < 4; ++q) {
                    const float lo = (float)((ww >> (8 * q)) & 15u);
                    const float hi = (float)((ww >> (8 * q + 4)) & 15u);
                    t[q] = (int)pkbf2(fmaf(lo, s, nzs), fmaf(hi, s, nzs));
                }
                fr[j][kh] = __builtin_bit_cast(s16x8, t);
            }
        }
    };
    auto comp = [&](const u16* Asr, s16x8 fr[2][2]) {
#pragma unroll
        for (int kh = 0; kh < 2; ++kh) {
            const int cc = kh * 4 + quad;
            s16x8 af[8];
#pragma unroll
            for (int i = 0; i < 8; ++i) {
                const int r = i * 16 + lr;
                af[i] = *(const s16x8*)&Asr[r * 64 + ((cc ^ (r & 7)) << 3)];
            }
#pragma unroll
            for (int i = 0; i < 8; ++i) {
                acc[i][0] = MFMA16(af[i], fr[0][kh], acc[i][0]);
                acc[i][1] = MFMA16(af[i], fr[1][kh], acc[i][1]);
            }
        }
    };

    // prologue
    u32 wrX[4], wrY[4];
    float svX[2], zvX[2], svY[2], zvY[2];
    s16x8 frX[2][2], frY[2][2];
    loadW(wrX, svX, zvX, 0);
    loadW(wrY, svY, zvY, 1);
    dmaA(As0, 0);
    dqfrag(frX, wrX, svX, zvX);        // frags for k=0
    loadW(wrX, svX, zvX, 2);
    __syncthreads();

    for (int kt = 0; kt < KT; kt += 2) {
        // stage: A(kt+1)->As1, frags(kt+1) from wrY; compute k=kt on As0/frX
        dmaA(As1, kt + 1);
        dqfrag(frY, wrY, svY, zvY);
        loadW(wrY, svY, zvY, kt + 3);
        comp(As0, frX);
        __syncthreads();
        // stage: A(kt+2)->As0, frags(kt+2) from wrX; compute k=kt+1 on As1/frY
        dmaA(As0, kt + 2);
        dqfrag(frX, wrX, svX, zvX);
        loadW(wrX, svX, zvX, kt + 4);
        comp(As1, frY);
        __syncthreads();
    }

    // epilogue: C row = m0 + i*16 + quad*4 + r ; col = n0 + w*32 + j*16 + lr
#pragma unroll
    for (int i = 0; i < 8; ++i) {
        const int rr0 = m0 + i * 16 + (quad << 2);
#pragma unroll
        for (int j = 0; j < 2; ++j) {
            const int cc = n0 + w * 32 + j * 16 + lr;
#pragma unroll
            for (int r = 0; r < 4; ++r) {
                const int row = rr0 + r;
                const float v = acc[i][j][r];
                if (epi == 0) {
                    ((u16*)outp)[(size_t)row * ldc + cc] = f2bf(v);
                } else if (epi == 1) {
                    ((u16*)outp)[((size_t)((row >> 10 << 10) + cc)) * 1024 + (row & 1023)] = f2bf(v);
                } else if (epi == 2) {
                    ((float*)outp)[(size_t)row * ldc + cc] = v + resid[(size_t)row * ldc + cc];
                } else {
                    const float t = v > 0.f ? v : 0.f;
                    ((u16*)outp)[(size_t)row * ldc + cc] = f2bf(t * t);
                }
            }
        }
    }
}

template<int KDIM>
__global__ __launch_bounds__(256, 2)
void gemm_w4(const u16* __restrict__ A, const u32* __restrict__ W,
             const float* __restrict__ Sc, const float* __restrict__ Zp,
             void* __restrict__ outp, const float* __restrict__ resid, int ldc, int epi)
{
    gemm_core<KDIM>(A, W, Sc, Zp, outp, resid, ldc, epi, blockIdx.x << 7, blockIdx.y << 7);
}

// fused QKV: ny 0..31 -> Q, 32..39 -> K, 40..47 -> V(transposed)
__global__ __launch_bounds__(256, 2)
void qkv_w4(const u16* __restrict__ A,
            const u32* __restrict__ qW, const float* __restrict__ qS, const float* __restrict__ qZ,
            const u32* __restrict__ kW, const float* __restrict__ kS, const float* __restrict__ kZ,
            const u32* __restrict__ vW, const float* __restrict__ vS, const float* __restrict__ vZ,
            u16* __restrict__ qout, u16* __restrict__ kout, u16* __restrict__ vtout)
{
    const int ny = blockIdx.y;
    const int m0 = blockIdx.x << 7;
    if (ny < 32)
        gemm_core<4096>(A, qW, qS, qZ, (void*)qout, nullptr, 4096, 0, m0, ny << 7);
    else if (ny < 40)
        gemm_core<4096>(A, kW, kS, kZ, (void*)kout, nullptr, 1024, 0, m0, (ny - 32) << 7);
    else
        gemm_core<4096>(A, vW, vS, vZ, (void*)vtout, nullptr, 1024, 1, m0, (ny - 40) << 7);
}

// ---------- Flash attention (causal, GQA 32q/8kv, HD=128, S=1024) ----------
__global__ __launch_bounds__(256)
void attn_k(const u16* __restrict__ Q, const u16* __restrict__ K,
            const u16* __restrict__ Vt, u16* __restrict__ O)
{
    const int qt = blockIdx.x, h = blockIdx.y, b = blockIdx.z;
    const int kh = h >> 2;
    const int tid = threadIdx.x, w = tid >> 6, l = tid & 63;
    const int quad = l >> 4, lr = l & 15;
    const int q0 = qt << 6;

    __shared__ __align__(16) u16 Qs[64 * 128];
    __shared__ __align__(16) u16 Ks[64 * 128];
    __shared__ __align__(16) u16 Vs[128 * 64];
    __shared__ __align__(16) u16 Ps[64 * 72];

#pragma unroll
    for (int i = 0; i < 4; ++i) {
        const int L = i * 256 + w * 64 + l;
        const int row = L >> 4, cl = L & 15;
        const int c = cl ^ (row & 15);
        gl2lds16(Q + ((size_t)(b * 1024 + q0 + row) * 4096 + h * 128 + c * 8),
                 &Qs[(i * 256 + w * 64) * 8]);
    }
    __syncthreads();
    s16x8 qf[4];
#pragma unroll
    for (int ks = 0; ks < 4; ++ks) {
        const int rq = w * 16 + lr;
        const int c = ks * 4 + quad;
        qf[ks] = *(const s16x8*)&Qs[rq * 128 + ((c ^ (rq & 15)) << 3)];
    }

    float m_i[4] = {-__builtin_inff(), -__builtin_inff(), -__builtin_inff(), -__builtin_inff()};
    float l_i[4] = {0.f, 0.f, 0.f, 0.f};
    f32x4 oa[8] = {};

    for (int n0 = 0; n0 <= q0; n0 += 64) {
        __syncthreads();
#pragma unroll
        for (int i = 0; i < 4; ++i) {
            const int L = i * 256 + w * 64 + l;
            const int row = L >> 4, cl = L & 15;
            const int c = cl ^ (row & 15);
            gl2lds16(K + ((size_t)(b * 1024 + n0 + row) * 1024 + kh * 128 + c * 8),
                     &Ks[(i * 256 + w * 64) * 8]);
        }
#pragma unroll
        for (int i = 0; i < 4; ++i) {
            const int L = i * 256 + w * 64 + l;
            const int d = L >> 3, cl = L & 7;
            const int c = cl ^ (d & 7);
            gl2lds16(Vt + ((size_t)((b * 8 + kh) * 128 + d) * 1024 + n0 + c * 8),
                     &Vs[(i * 256 + w * 64) * 8]);
        }
        __syncthreads();

        f32x4 sc[4] = {};
#pragma unroll
        for (int ks = 0; ks < 4; ++ks) {
#pragma unroll
            for (int ni = 0; ni < 4; ++ni) {
                const int n = ni * 16 + lr;
                const int c = ks * 4 + quad;
                s16x8 bk = *(const s16x8*)&Ks[n * 128 + ((c ^ (n & 15)) << 3)];
                sc[ni] = MFMA16(qf[ks], bk, sc[ni]);
            }
        }
        const float scale = 0.08838834764831845f;
        const bool diag = (n0 == q0);
#pragma unroll
        for (int ni = 0; ni < 4; ++ni) {
            const int nabs = n0 + ni * 16 + lr;
#pragma unroll
            for (int r = 0; r < 4; ++r) {
                float vv = sc[ni][r] * scale;
                if (diag && nabs > q0 + w * 16 + quad * 4 + r) vv = -__builtin_inff();
                sc[ni][r] = vv;
            }
        }
        float alpha[4];
#pragma unroll
        for (int r = 0; r < 4; ++r) {
            float mx = fmaxf(fmaxf(sc[0][r], sc[1][r]), fmaxf(sc[2][r], sc[3][r]));
            mx = fmaxf(mx, __shfl_xor(mx, 1));
            mx = fmaxf(mx, __shfl_xor(mx, 2));
            mx = fmaxf(mx, __shfl_xor(mx, 4));
            mx = fmaxf(mx, __shfl_xor(mx, 8));
            const float mn = fmaxf(m_i[r], mx);
            alpha[r] = __expf(m_i[r] - mn);
            m_i[r] = mn;
#pragma unroll
            for (int ni = 0; ni < 4; ++ni) sc[ni][r] = __expf(sc[ni][r] - mn);
            float sr = sc[0][r] + sc[1][r] + sc[2][r] + sc[3][r];
            sr += __shfl_xor(sr, 1); sr += __shfl_xor(sr, 2);
            sr += __shfl_xor(sr, 4); sr += __shfl_xor(sr, 8);
            l_i[r] = l_i[r] * alpha[r] + sr;
        }
#pragma unroll
        for (int dt = 0; dt < 8; ++dt)
#pragma unroll
            for (int r = 0; r < 4; ++r) oa[dt][r] *= alpha[r];
#pragma unroll
        for (int ni = 0; ni < 4; ++ni)
#pragma unroll
            for (int r = 0; r < 4; ++r)
                Ps[(w * 16 + quad * 4 + r) * 72 + ni * 16 + lr] = f2bf(sc[ni][r]);
        __syncthreads();
#pragma unroll
        for (int ks = 0; ks < 2; ++ks) {
            s16x8 pa = *(const s16x8*)&Ps[(w * 16 + lr) * 72 + ks * 32 + (quad << 3)];
#pragma unroll
            for (int dt = 0; dt < 8; ++dt) {
                const int d = dt * 16 + lr;
                const int c = ks * 4 + quad;
                s16x8 bv = *(const s16x8*)&Vs[(d << 6) + ((c ^ (d & 7)) << 3)];
                oa[dt] = MFMA16(pa, bv, oa[dt]);
            }
        }
    }
#pragma unroll
    for (int dt = 0; dt < 8; ++dt) {
#pragma unroll
        for (int r = 0; r < 4; ++r) {
            const int row = q0 + w * 16 + quad * 4 + r;
            const int col = h * 128 + dt * 16 + lr;
            O[(size_t)(b * 1024 + row) * 4096 + col] = f2bf(oa[dt][r] / l_i[r]);
        }
    }
}

// ---------- launch ----------
extern "C" void kernel_launch(void* const* d_in, const int* in_sizes, int n_in,
                              void* d_out, int out_size, void* d_ws, size_t ws_size,
                              hipStream_t stream)
{
    (void)in_sizes; (void)n_in; (void)out_size; (void)ws_size;
    const float* hidden = (const float*)d_in[0];
    const float* ln1 = (const float*)d_in[1];
    const float* ln2 = (const float*)d_in[2];
    const int*   q_qw = (const int*)d_in[3];
    const float* q_s  = (const float*)d_in[4];
    const float* q_z  = (const float*)d_in[5];
    const int*   k_qw = (const int*)d_in[6];
    const float* k_s  = (const float*)d_in[7];
    const float* k_z  = (const float*)d_in[8];
    const int*   v_qw = (const int*)d_in[9];
    const float* v_s  = (const float*)d_in[10];
    const float* v_z  = (const float*)d_in[11];
    const int*   o_qw = (const int*)d_in[12];
    const float* o_s  = (const float*)d_in[13];
    const float* o_z  = (const float*)d_in[14];
    const int*   up_qw = (const int*)d_in[15];
    const float* up_s  = (const float*)d_in[16];
    const float* up_z  = (const float*)d_in[17];
    const int*   dn_qw = (const int*)d_in[18];
    const float* dn_s  = (const float*)d_in[19];
    const float* dn_z  = (const float*)d_in[20];
    float* out = (float*)d_out;
    char* ws = (char*)d_ws;

    // ---- workspace layout ----
    float* x_buf  = (float*)(ws);                 // f32 [2048][4096]   0..32M
    u16* h_buf    = (u16*)(ws + 33554432);        // bf16 [2048][4096]  32..48M (h and h2)
    u32* P        = (u32*)(ws + 50331648);        // packed-weight pool 48..77.4M
    u16* q_buf    = (u16*)(ws + 79691776);        // attn-phase buffers
    u16* k_buf    = (u16*)(ws + 96468992);
    u16* vt_buf   = (u16*)(ws + 100663296);
    u16* attn_buf = (u16*)(ws + 104857600);
    u16* act_buf  = (u16*)(ws + 79691776);        // overlays q/k/vt/attn in MLP phase
    u16* h2_buf   = h_buf;

    // packed sub-buffers (pool reused sequentially: {q,k,v} -> o -> up -> dn)
    u32* Pq  = P;                  // 4096*512  u32
    u32* Pk  = P + 2097152;        // 1024*512
    u32* Pv  = P + 2621440;        // 1024*512
    u32* Po  = P;                  // 4096*512
    u32* Pup = P;                  // 14336*512
    u32* Pdn = P;                  // 4096*1792

    // attention phase
    pack_w4<<<2048, 256, 0, stream>>>(q_qw, Pq, 4096 * 512);
    pack_w4<<<1024, 256, 0, stream>>>(k_qw, Pk, 1024 * 512);
    pack_w4<<<1024, 256, 0, stream>>>(v_qw, Pv, 1024 * 512);
    rmsnorm_k<<<2048, 256, 0, stream>>>(hidden, ln1, h_buf);
    qkv_w4<<<dim3(16, 48), 256, 32768, stream>>>(h_buf,
        Pq, q_s, q_z, Pk, k_s, k_z, Pv, v_s, v_z,
        q_buf, k_buf, vt_buf);
    attn_k<<<dim3(16, 32, 2), 256, 0, stream>>>(q_buf, k_buf, vt_buf, attn_buf);
    pack_w4<<<2048, 256, 0, stream>>>(o_qw, Po, 4096 * 512);
    gemm_w4<4096><<<dim3(16, 32), 256, 32768, stream>>>(attn_buf, Po, o_s, o_z,
        (void*)x_buf, hidden, 4096, 2);

    // MLP phase
    rmsnorm_k<<<2048, 256, 0, stream>>>(x_buf, ln2, h2_buf);
    pack_w4<<<2048, 256, 0, stream>>>(up_qw, Pup, 14336 * 512);
    gemm_w4<4096><<<dim3(16, 112), 256, 32768, stream>>>(h2_buf, Pup, up_s, up_z,
        (void*)act_buf, nullptr, 14336, 3);
    pack_w4<<<2048, 256, 0, stream>>>(dn_qw, Pdn, 4096 * 1792);
    gemm_w4<14336><<<dim3(16, 32), 256, 32768, stream>>>(act_buf, Pdn, dn_s, dn_z,
        (void*)out, x_buf, 4096, 2);
}

// Round 4
// 2133.087 us; speedup vs baseline: 1.4397x; 1.0422x over previous
//
#include <hip/hip_runtime.h>

typedef unsigned short u16;
typedef unsigned int   u32;
typedef short  s16x8 __attribute__((ext_vector_type(8)));
typedef int    i32x4 __attribute__((ext_vector_type(4)));
typedef float  f32x4 __attribute__((ext_vector_type(4)));

// ---------- helpers ----------
__device__ __forceinline__ u16 f2bf(float f) {
    u32 u = __builtin_bit_cast(u32, f);
    u += 0x7FFFu + ((u >> 16) & 1u);   // RNE
    return (u16)(u >> 16);
}

__device__ __forceinline__ u32 pkbf2(float a, float b) {
    return (u32)f2bf(a) | ((u32)f2bf(b) << 16);
}

// HW packed f32x2 -> bf16x2 (RNE), single VOP3 instruction. No builtin on gfx950;
// compiler cannot derive it from the bit-twiddle RNE, so inline asm (non-volatile
// so the scheduler may move it freely).
__device__ __forceinline__ u32 cvtpk_bf16(float lo, float hi) {
    u32 r;
    asm("v_cvt_pk_bf16_f32 %0, %1, %2" : "=v"(r) : "v"(lo), "v"(hi));
    return r;
}

__device__ __forceinline__ void gl2lds16(const void* g, void* l) {
    __builtin_amdgcn_global_load_lds((const __attribute__((address_space(1))) void*)g,
                                     (__attribute__((address_space(3))) void*)l, 16, 0, 0);
}

#define MFMA16(a, b, c) __builtin_amdgcn_mfma_f32_16x16x32_bf16((a), (b), (c), 0, 0, 0)

// ---------- weight repack: int32 [O,I] (one int4/elem) -> u32 [O, I/8] (linear) ----------
__global__ __launch_bounds__(256)
void pack_w4(const int* __restrict__ W, u32* __restrict__ P, int n8)
{
    for (int i = blockIdx.x * 256 + threadIdx.x; i < n8; i += gridDim.x * 256) {
        const int4* p = (const int4*)(W + (size_t)i * 8);
        const int4 a = p[0], b = p[1];
        const u32 r = ((u32)a.x & 15u)         | (((u32)a.y & 15u) << 4)
                    | (((u32)a.z & 15u) << 8)  | (((u32)a.w & 15u) << 12)
                    | (((u32)b.x & 15u) << 16) | (((u32)b.y & 15u) << 20)
                    | (((u32)b.z & 15u) << 24) | (((u32)b.w & 15u) << 28);
        P[i] = r;
    }
}

// ---------- RMSNorm: f32 [T,4096] -> bf16 [T,4096] ----------
__global__ __launch_bounds__(256)
void rmsnorm_k(const float* __restrict__ x, const float* __restrict__ g, u16* __restrict__ o)
{
    const int t = blockIdx.x;
    const int tid = threadIdx.x;
    const float4* row = (const float4*)(x + (size_t)t * 4096);
    float4 v[4];
    float ss = 0.f;
#pragma unroll
    for (int i = 0; i < 4; ++i) {
        v[i] = row[tid + i * 256];
        ss += v[i].x * v[i].x + v[i].y * v[i].y + v[i].z * v[i].z + v[i].w * v[i].w;
    }
#pragma unroll
    for (int off = 32; off >= 1; off >>= 1) ss += __shfl_xor(ss, off);
    __shared__ float red[4];
    if ((tid & 63) == 0) red[tid >> 6] = ss;
    __syncthreads();
    const float tot = red[0] + red[1] + red[2] + red[3];
    const float rs = rsqrtf(tot * (1.0f / 4096.0f) + 1e-5f);
    const float4* gw = (const float4*)g;
    uint2* orow = (uint2*)(o + (size_t)t * 4096);
#pragma unroll
    for (int i = 0; i < 4; ++i) {
        float4 wv = gw[tid + i * 256];
        uint2 pk;
        pk.x = pkbf2(v[i].x * rs * wv.x, v[i].y * rs * wv.y);
        pk.y = pkbf2(v[i].z * rs * wv.z, v[i].w * rs * wv.w);
        orow[tid + i * 256] = pk;
    }
}

// ---------- W4A16 GEMM core (packed weights, linear layout) ----------
// BM=BN=128, BK=64, 256 threads. Wave w owns output cols [w*32, w*32+32).
// A: LDS double-buffer (2 x 16 KB), async DMA. W: nibble-packed u32 (8 wt/u32),
// dequantized directly into MFMA B-fragments in registers (v_cvt_pk_bf16_f32).
// One barrier per K-step.
// epi 0: bf16 row-major; epi 1: bf16 V-transposed; epi 2: f32 +resid; epi 3: bf16 relu^2
template<int KDIM>
__device__ __forceinline__ void gemm_core(
    const u16* __restrict__ A, const u32* __restrict__ W,
    const float* __restrict__ Sc, const float* __restrict__ Zp,
    void* __restrict__ outp, const float* __restrict__ resid,
    int ldc, int epi, int m0, int n0)
{
    constexpr int NG = KDIM / 128;
    constexpr int KT = KDIM / 64;          // K-steps
    constexpr int KP = KDIM / 8;           // packed u32 per weight row
    const int tid = threadIdx.x;
    const int w = tid >> 6, l = tid & 63;
    const int quad = l >> 4, lr = l & 15;

    extern __shared__ char smem[];
    u16* const As0 = (u16*)smem;           // 128 x 64, chunk-xor swizzle
    u16* const As1 = (u16*)(smem + 16384);

    // A DMA mapping: issue i covers rows seg..seg+7; lane l -> row seg+(l>>3), phys chunk l&7
    const int ar = l >> 3;
    const int ac = (l & 7) ^ ar;           // fetch global chunk so phys = global ^ (row&7)

    // W per-lane fragment rows: j=0,1 -> n0 + w*32 + j*16 + lr; k offset quad*8
    const int nr0 = n0 + w * 32 + lr;
    const int nr1 = nr0 + 16;
    const u32* Wp0 = W + (size_t)nr0 * KP + quad;
    const u32* Wp1 = W + (size_t)nr1 * KP + quad;
    const float* Sb0 = Sc + (size_t)nr0 * NG;
    const float* Zb0 = Zp + (size_t)nr0 * NG;
    const float* Sb1 = Sc + (size_t)nr1 * NG;
    const float* Zb1 = Zp + (size_t)nr1 * NG;

    f32x4 acc[8][2] = {};

    // wr[0..1]: row nr0 kh=0/1; wr[2..3]: row nr1 kh=0/1. u32 idx = kk*8 + kh*4 + quad.
    auto loadW = [&](u32 wr[4], float* sv, float* zv, int ki) {
        const int kk = (ki < KT) ? ki : 0;
        const int k8 = kk << 3, g = kk >> 1;
        wr[0] = Wp0[k8]; wr[1] = Wp0[k8 + 4];
        wr[2] = Wp1[k8]; wr[3] = Wp1[k8 + 4];
        sv[0] = Sb0[g]; zv[0] = Zb0[g];
        sv[1] = Sb1[g]; zv[1] = Zb1[g];
    };
    auto dmaA = [&](u16* dst, int ki) {
        const int k0 = ((ki < KT) ? ki : 0) << 6;
#pragma unroll
        for (int i = 0; i < 4; ++i) {
            const int seg = (w * 4 + i) * 8;
            gl2lds16(A + (size_t)(m0 + seg + ar) * KDIM + k0 + ac * 8, &dst[seg * 64]);
        }
    };
    auto dqfrag = [&](s16x8 fr[2][2], const u32 wr[4], const float* sv, const float* zv) {
#pragma unroll
        for (int j = 0; j < 2; ++j) {
            const float s = sv[j], nzs = -zv[j] * sv[j];
#pragma unroll
            for (int kh = 0; kh < 2; ++kh) {
                const u32 ww = wr[j * 2 + kh];
                i32x4 t;
#pragma unroll
                for (int q = 0; q < 4; ++q) {
                    const float lo = (float)((ww >> (8 * q)) & 15u);
                    const float hi = (float)((ww >> (8 * q + 4)) & 15u);
                    t[q] = (int)cvtpk_bf16(fmaf(lo, s, nzs), fmaf(hi, s, nzs));
                }
                fr[j][kh] = __builtin_bit_cast(s16x8, t);
            }
        }
    };
    auto comp = [&](const u16* Asr, s16x8 fr[2][2]) {
#pragma unroll
        for (int kh = 0; kh < 2; ++kh) {
            const int cc = kh * 4 + quad;
            s16x8 af[8];
#pragma unroll
            for (int i = 0; i < 8; ++i) {
                const int r = i * 16 + lr;
                af[i] = *(const s16x8*)&Asr[r * 64 + ((cc ^ (r & 7)) << 3)];
            }
#pragma unroll
            for (int i = 0; i < 8; ++i) {
                acc[i][0] = MFMA16(af[i], fr[0][kh], acc[i][0]);
                acc[i][1] = MFMA16(af[i], fr[1][kh], acc[i][1]);
            }
        }
    };

    // prologue
    u32 wrX[4], wrY[4];
    float svX[2], zvX[2], svY[2], zvY[2];
    s16x8 frX[2][2], frY[2][2];
    loadW(wrX, svX, zvX, 0);
    loadW(wrY, svY, zvY, 1);
    dmaA(As0, 0);
    dqfrag(frX, wrX, svX, zvX);        // frags for k=0
    loadW(wrX, svX, zvX, 2);
    __syncthreads();

    for (int kt = 0; kt < KT; kt += 2) {
        // stage: A(kt+1)->As1, frags(kt+1) from wrY; compute k=kt on As0/frX
        dmaA(As1, kt + 1);
        dqfrag(frY, wrY, svY, zvY);
        loadW(wrY, svY, zvY, kt + 3);
        comp(As0, frX);
        __syncthreads();
        // stage: A(kt+2)->As0, frags(kt+2) from wrX; compute k=kt+1 on As1/frY
        dmaA(As0, kt + 2);
        dqfrag(frX, wrX, svX, zvX);
        loadW(wrX, svX, zvX, kt + 4);
        comp(As1, frY);
        __syncthreads();
    }

    // epilogue: C row = m0 + i*16 + quad*4 + r ; col = n0 + w*32 + j*16 + lr
#pragma unroll
    for (int i = 0; i < 8; ++i) {
        const int rr0 = m0 + i * 16 + (quad << 2);
#pragma unroll
        for (int j = 0; j < 2; ++j) {
            const int cc = n0 + w * 32 + j * 16 + lr;
#pragma unroll
            for (int r = 0; r < 4; ++r) {
                const int row = rr0 + r;
                const float v = acc[i][j][r];
                if (epi == 0) {
                    ((u16*)outp)[(size_t)row * ldc + cc] = f2bf(v);
                } else if (epi == 1) {
                    ((u16*)outp)[((size_t)((row >> 10 << 10) + cc)) * 1024 + (row & 1023)] = f2bf(v);
                } else if (epi == 2) {
                    ((float*)outp)[(size_t)row * ldc + cc] = v + resid[(size_t)row * ldc + cc];
                } else {
                    const float t = v > 0.f ? v : 0.f;
                    ((u16*)outp)[(size_t)row * ldc + cc] = f2bf(t * t);
                }
            }
        }
    }
}

template<int KDIM>
__global__ __launch_bounds__(256, 2)
void gemm_w4(const u16* __restrict__ A, const u32* __restrict__ W,
             const float* __restrict__ Sc, const float* __restrict__ Zp,
             void* __restrict__ outp, const float* __restrict__ resid, int ldc, int epi)
{
    gemm_core<KDIM>(A, W, Sc, Zp, outp, resid, ldc, epi, blockIdx.x << 7, blockIdx.y << 7);
}

// fused QKV: ny 0..31 -> Q, 32..39 -> K, 40..47 -> V(transposed)
__global__ __launch_bounds__(256, 2)
void qkv_w4(const u16* __restrict__ A,
            const u32* __restrict__ qW, const float* __restrict__ qS, const float* __restrict__ qZ,
            const u32* __restrict__ kW, const float* __restrict__ kS, const float* __restrict__ kZ,
            const u32* __restrict__ vW, const float* __restrict__ vS, const float* __restrict__ vZ,
            u16* __restrict__ qout, u16* __restrict__ kout, u16* __restrict__ vtout)
{
    const int ny = blockIdx.y;
    const int m0 = blockIdx.x << 7;
    if (ny < 32)
        gemm_core<4096>(A, qW, qS, qZ, (void*)qout, nullptr, 4096, 0, m0, ny << 7);
    else if (ny < 40)
        gemm_core<4096>(A, kW, kS, kZ, (void*)kout, nullptr, 1024, 0, m0, (ny - 32) << 7);
    else
        gemm_core<4096>(A, vW, vS, vZ, (void*)vtout, nullptr, 1024, 1, m0, (ny - 40) << 7);
}

// ---------- Flash attention (causal, GQA 32q/8kv, HD=128, S=1024) ----------
__global__ __launch_bounds__(256)
void attn_k(const u16* __restrict__ Q, const u16* __restrict__ K,
            const u16* __restrict__ Vt, u16* __restrict__ O)
{
    const int qt = blockIdx.x, h = blockIdx.y, b = blockIdx.z;
    const int kh = h >> 2;
    const int tid = threadIdx.x, w = tid >> 6, l = tid & 63;
    const int quad = l >> 4, lr = l & 15;
    const int q0 = qt << 6;

    __shared__ __align__(16) u16 Qs[64 * 128];
    __shared__ __align__(16) u16 Ks[64 * 128];
    __shared__ __align__(16) u16 Vs[128 * 64];
    __shared__ __align__(16) u16 Ps[64 * 72];

#pragma unroll
    for (int i = 0; i < 4; ++i) {
        const int L = i * 256 + w * 64 + l;
        const int row = L >> 4, cl = L & 15;
        const int c = cl ^ (row & 15);
        gl2lds16(Q + ((size_t)(b * 1024 + q0 + row) * 4096 + h * 128 + c * 8),
                 &Qs[(i * 256 + w * 64) * 8]);
    }
    __syncthreads();
    s16x8 qf[4];
#pragma unroll
    for (int ks = 0; ks < 4; ++ks) {
        const int rq = w * 16 + lr;
        const int c = ks * 4 + quad;
        qf[ks] = *(const s16x8*)&Qs[rq * 128 + ((c ^ (rq & 15)) << 3)];
    }

    float m_i[4] = {-__builtin_inff(), -__builtin_inff(), -__builtin_inff(), -__builtin_inff()};
    float l_i[4] = {0.f, 0.f, 0.f, 0.f};
    f32x4 oa[8] = {};

    for (int n0 = 0; n0 <= q0; n0 += 64) {
        __syncthreads();
#pragma unroll
        for (int i = 0; i < 4; ++i) {
            const int L = i * 256 + w * 64 + l;
            const int row = L >> 4, cl = L & 15;
            const int c = cl ^ (row & 15);
            gl2lds16(K + ((size_t)(b * 1024 + n0 + row) * 1024 + kh * 128 + c * 8),
                     &Ks[(i * 256 + w * 64) * 8]);
        }
#pragma unroll
        for (int i = 0; i < 4; ++i) {
            const int L = i * 256 + w * 64 + l;
            const int d = L >> 3, cl = L & 7;
            const int c = cl ^ (d & 7);
            gl2lds16(Vt + ((size_t)((b * 8 + kh) * 128 + d) * 1024 + n0 + c * 8),
                     &Vs[(i * 256 + w * 64) * 8]);
        }
        __syncthreads();

        f32x4 sc[4] = {};
#pragma unroll
        for (int ks = 0; ks < 4; ++ks) {
#pragma unroll
            for (int ni = 0; ni < 4; ++ni) {
                const int n = ni * 16 + lr;
                const int c = ks * 4 + quad;
                s16x8 bk = *(const s16x8*)&Ks[n * 128 + ((c ^ (n & 15)) << 3)];
                sc[ni] = MFMA16(qf[ks], bk, sc[ni]);
            }
        }
        const float scale = 0.08838834764831845f;
        const bool diag = (n0 == q0);
#pragma unroll
        for (int ni = 0; ni < 4; ++ni) {
            const int nabs = n0 + ni * 16 + lr;
#pragma unroll
            for (int r = 0; r < 4; ++r) {
                float vv = sc[ni][r] * scale;
                if (diag && nabs > q0 + w * 16 + quad * 4 + r) vv = -__builtin_inff();
                sc[ni][r] = vv;
            }
        }
        float alpha[4];
#pragma unroll
        for (int r = 0; r < 4; ++r) {
            float mx = fmaxf(fmaxf(sc[0][r], sc[1][r]), fmaxf(sc[2][r], sc[3][r]));
            mx = fmaxf(mx, __shfl_xor(mx, 1));
            mx = fmaxf(mx, __shfl_xor(mx, 2));
            mx = fmaxf(mx, __shfl_xor(mx, 4));
            mx = fmaxf(mx, __shfl_xor(mx, 8));
            const float mn = fmaxf(m_i[r], mx);
            alpha[r] = __expf(m_i[r] - mn);
            m_i[r] = mn;
#pragma unroll
            for (int ni = 0; ni < 4; ++ni) sc[ni][r] = __expf(sc[ni][r] - mn);
            float sr = sc[0][r] + sc[1][r] + sc[2][r] + sc[3][r];
            sr += __shfl_xor(sr, 1); sr += __shfl_xor(sr, 2);
            sr += __shfl_xor(sr, 4); sr += __shfl_xor(sr, 8);
            l_i[r] = l_i[r] * alpha[r] + sr;
        }
#pragma unroll
        for (int dt = 0; dt < 8; ++dt)
#pragma unroll
            for (int r = 0; r < 4; ++r) oa[dt][r] *= alpha[r];
#pragma unroll
        for (int ni = 0; ni < 4; ++ni)
#pragma unroll
            for (int r = 0; r < 4; ++r)
                Ps[(w * 16 + quad * 4 + r) * 72 + ni * 16 + lr] = f2bf(sc[ni][r]);
        __syncthreads();
#pragma unroll
        for (int ks = 0; ks < 2; ++ks) {
            s16x8 pa = *(const s16x8*)&Ps[(w * 16 + lr) * 72 + ks * 32 + (quad << 3)];
#pragma unroll
            for (int dt = 0; dt < 8; ++dt) {
                const int d = dt * 16 + lr;
                const int c = ks * 4 + quad;
                s16x8 bv = *(const s16x8*)&Vs[(d << 6) + ((c ^ (d & 7)) << 3)];
                oa[dt] = MFMA16(pa, bv, oa[dt]);
            }
        }
    }
#pragma unroll
    for (int dt = 0; dt < 8; ++dt) {
#pragma unroll
        for (int r = 0; r < 4; ++r) {
            const int row = q0 + w * 16 + quad * 4 + r;
            const int col = h * 128 + dt * 16 + lr;
            O[(size_t)(b * 1024 + row) * 4096 + col] = f2bf(oa[dt][r] / l_i[r]);
        }
    }
}

// ---------- launch ----------
extern "C" void kernel_launch(void* const* d_in, const int* in_sizes, int n_in,
                              void* d_out, int out_size, void* d_ws, size_t ws_size,
                              hipStream_t stream)
{
    (void)in_sizes; (void)n_in; (void)out_size; (void)ws_size;
    const float* hidden = (const float*)d_in[0];
    const float* ln1 = (const float*)d_in[1];
    const float* ln2 = (const float*)d_in[2];
    const int*   q_qw = (const int*)d_in[3];
    const float* q_s  = (const float*)d_in[4];
    const float* q_z  = (const float*)d_in[5];
    const int*   k_qw = (const int*)d_in[6];
    const float* k_s  = (const float*)d_in[7];
    const float* k_z  = (const float*)d_in[8];
    const int*   v_qw = (const int*)d_in[9];
    const float* v_s  = (const float*)d_in[10];
    const float* v_z  = (const float*)d_in[11];
    const int*   o_qw = (const int*)d_in[12];
    const float* o_s  = (const float*)d_in[13];
    const float* o_z  = (const float*)d_in[14];
    const int*   up_qw = (const int*)d_in[15];
    const float* up_s  = (const float*)d_in[16];
    const float* up_z  = (const float*)d_in[17];
    const int*   dn_qw = (const int*)d_in[18];
    const float* dn_s  = (const float*)d_in[19];
    const float* dn_z  = (const float*)d_in[20];
    float* out = (float*)d_out;
    char* ws = (char*)d_ws;

    // ---- workspace layout ----
    float* x_buf  = (float*)(ws);                 // f32 [2048][4096]   0..32M
    u16* h_buf    = (u16*)(ws + 33554432);        // bf16 [2048][4096]  32..48M (h and h2)
    u32* P        = (u32*)(ws + 50331648);        // packed-weight pool 48..77.4M
    u16* q_buf    = (u16*)(ws + 79691776);        // attn-phase buffers
    u16* k_buf    = (u16*)(ws + 96468992);
    u16* vt_buf   = (u16*)(ws + 100663296);
    u16* attn_buf = (u16*)(ws + 104857600);
    u16* act_buf  = (u16*)(ws + 79691776);        // overlays q/k/vt/attn in MLP phase
    u16* h2_buf   = h_buf;

    // packed sub-buffers (pool reused sequentially: {q,k,v} -> o -> up -> dn)
    u32* Pq  = P;                  // 4096*512  u32
    u32* Pk  = P + 2097152;        // 1024*512
    u32* Pv  = P + 2621440;        // 1024*512
    u32* Po  = P;                  // 4096*512
    u32* Pup = P;                  // 14336*512
    u32* Pdn = P;                  // 4096*1792

    // attention phase
    pack_w4<<<2048, 256, 0, stream>>>(q_qw, Pq, 4096 * 512);
    pack_w4<<<1024, 256, 0, stream>>>(k_qw, Pk, 1024 * 512);
    pack_w4<<<1024, 256, 0, stream>>>(v_qw, Pv, 1024 * 512);
    rmsnorm_k<<<2048, 256, 0, stream>>>(hidden, ln1, h_buf);
    qkv_w4<<<dim3(16, 48), 256, 32768, stream>>>(h_buf,
        Pq, q_s, q_z, Pk, k_s, k_z, Pv, v_s, v_z,
        q_buf, k_buf, vt_buf);
    attn_k<<<dim3(16, 32, 2), 256, 0, stream>>>(q_buf, k_buf, vt_buf, attn_buf);
    pack_w4<<<2048, 256, 0, stream>>>(o_qw, Po, 4096 * 512);
    gemm_w4<4096><<<dim3(16, 32), 256, 32768, stream>>>(attn_buf, Po, o_s, o_z,
        (void*)x_buf, hidden, 4096, 2);

    // MLP phase
    rmsnorm_k<<<2048, 256, 0, stream>>>(x_buf, ln2, h2_buf);
    pack_w4<<<2048, 256, 0, stream>>>(up_qw, Pup, 14336 * 512);
    gemm_w4<4096><<<dim3(16, 112), 256, 32768, stream>>>(h2_buf, Pup, up_s, up_z,
        (void*)act_buf, nullptr, 14336, 3);
    pack_w4<<<2048, 256, 0, stream>>>(dn_qw, Pdn, 4096 * 1792);
    gemm_w4<14336><<<dim3(16, 32), 256, 32768, stream>>>(act_buf, Pdn, dn_s, dn_z,
        (void*)out, x_buf, 4096, 2);
}